// Round 3
// baseline (261.358 us; speedup 1.0000x reference)
//
#include <hip/hip_runtime.h>
#include <math.h>

// ---------------- problem constants ----------------
#define ND 2048
#define NS 1024
#define DIN 768
#define DOUT 64
#define NSTEPS 20
static constexpr float BLUR2 = 0.05f * 0.05f; // blur^p, p=2

// ---------------- ws layout (float offsets) ----------------
// x rows [0,2048), y rows [2048,3072) contiguous, 64 cols each
#define OFF_X     0u              // 3072*64 = 196608
#define OFF_NRM   196608u         // 3072 (0.5*||row||^2), nx then ny
#define OFF_DIAM  199680u         // 1 (diameter^2), padded to 64
#define OFF_POT0  199744u         // 6144: [f_ab 2048 | g_ab 1024 | f_aa 2048 | g_bb 1024]
#define OFF_POT1  205888u         // 6144
#define OFF_CXY   212032u         // 2048*1024
#define OFF_CYX   2309184u        // 1024*2048
#define OFF_CXX   4406336u        // 2048*2048
#define OFF_CYY   8600640u        // 1024*1024  (end = 9649216 floats = 38.6 MB)
// min/max partials (768 blocks x [64 mins | 64 maxs]) live transiently in the
// C_xy region: written by proj_kernel, consumed by stats_kernel, then
// overwritten by build_cost.
#define OFF_PART  OFF_CXY

// ---------------- kernel 1: projection (K-split) + row sqnorms + per-block min/max ----
// 768 blocks x 4 waves. Block b owns rows 4b..4b+3; wave w owns K-chunk
// [192w, 192w+192). lane = output column. Partials combined via LDS.
__global__ __launch_bounds__(256) void proj_kernel(const float* __restrict__ d,
                                                   const float* __restrict__ s,
                                                   const float* __restrict__ M,
                                                   float* __restrict__ ws) {
  const int w    = threadIdx.x >> 6;
  const int lane = threadIdx.x & 63;
  const int r0   = blockIdx.x * 4; // rows r0..r0+3, all on same side of 2048

  const float* base;
  if (r0 < ND) base = d + (size_t)r0 * DIN;
  else         base = s + (size_t)(r0 - ND) * DIN;

  const float4* s0 = reinterpret_cast<const float4*>(base + 0 * DIN + w * 192);
  const float4* s1 = reinterpret_cast<const float4*>(base + 1 * DIN + w * 192);
  const float4* s2 = reinterpret_cast<const float4*>(base + 2 * DIN + w * 192);
  const float4* s3 = reinterpret_cast<const float4*>(base + 3 * DIN + w * 192);
  const float* Mw = M + (size_t)(w * 192) * DOUT + lane;

  float a0 = 0.f, a1 = 0.f, a2 = 0.f, a3 = 0.f;
#pragma unroll 4
  for (int kk = 0; kk < 48; ++kk) {
    const float4 r0v = s0[kk];
    const float4 r1v = s1[kk];
    const float4 r2v = s2[kk];
    const float4 r3v = s3[kk];
    const float m0 = Mw[(kk * 4 + 0) * DOUT];
    const float m1 = Mw[(kk * 4 + 1) * DOUT];
    const float m2 = Mw[(kk * 4 + 2) * DOUT];
    const float m3 = Mw[(kk * 4 + 3) * DOUT];
    a0 = fmaf(r0v.x, m0, a0); a0 = fmaf(r0v.y, m1, a0);
    a0 = fmaf(r0v.z, m2, a0); a0 = fmaf(r0v.w, m3, a0);
    a1 = fmaf(r1v.x, m0, a1); a1 = fmaf(r1v.y, m1, a1);
    a1 = fmaf(r1v.z, m2, a1); a1 = fmaf(r1v.w, m3, a1);
    a2 = fmaf(r2v.x, m0, a2); a2 = fmaf(r2v.y, m1, a2);
    a2 = fmaf(r2v.z, m2, a2); a2 = fmaf(r2v.w, m3, a2);
    a3 = fmaf(r3v.x, m0, a3); a3 = fmaf(r3v.y, m1, a3);
    a3 = fmaf(r3v.z, m2, a3); a3 = fmaf(r3v.w, m3, a3);
  }

  __shared__ float part[4][4][64];
  part[w][0][lane] = a0;
  part[w][1][lane] = a1;
  part[w][2][lane] = a2;
  part[w][3][lane] = a3;
  __syncthreads();

  if (w == 0) {
    const float f0 = part[0][0][lane] + part[1][0][lane] + part[2][0][lane] + part[3][0][lane];
    const float f1 = part[0][1][lane] + part[1][1][lane] + part[2][1][lane] + part[3][1][lane];
    const float f2 = part[0][2][lane] + part[1][2][lane] + part[2][2][lane] + part[3][2][lane];
    const float f3 = part[0][3][lane] + part[1][3][lane] + part[2][3][lane] + part[3][3][lane];

    float* xy = ws + OFF_X;
    xy[(size_t)(r0 + 0) * DOUT + lane] = f0;
    xy[(size_t)(r0 + 1) * DOUT + lane] = f1;
    xy[(size_t)(r0 + 2) * DOUT + lane] = f2;
    xy[(size_t)(r0 + 3) * DOUT + lane] = f3;

    // per-block per-dim min/max over the 4 final rows
    float* pmm = ws + OFF_PART;
    const float mn4 = fminf(fminf(f0, f1), fminf(f2, f3));
    const float mx4 = fmaxf(fmaxf(f0, f1), fmaxf(f2, f3));
    pmm[(size_t)blockIdx.x * 128 + lane]      = mn4;
    pmm[(size_t)blockIdx.x * 128 + 64 + lane] = mx4;

    float n0 = f0 * f0, n1 = f1 * f1, n2 = f2 * f2, n3 = f3 * f3;
#pragma unroll
    for (int off = 32; off > 0; off >>= 1) {
      n0 += __shfl_xor(n0, off, 64);
      n1 += __shfl_xor(n1, off, 64);
      n2 += __shfl_xor(n2, off, 64);
      n3 += __shfl_xor(n3, off, 64);
    }
    if (lane == 0) {
      float* nrm = ws + OFF_NRM;
      nrm[r0 + 0] = 0.5f * n0;
      nrm[r0 + 1] = 0.5f * n1;
      nrm[r0 + 2] = 0.5f * n2;
      nrm[r0 + 3] = 0.5f * n3;
    }
  }
}

// ---------------- kernel 2: combine per-block min/max -> diameter^2 ----------------
__global__ __launch_bounds__(256) void stats_kernel(float* __restrict__ ws) {
  const int tid = threadIdx.x;
  const int dim = tid & 63;
  const int grp = tid >> 6;
  const float* part = ws + OFF_PART;
  float mn = 3.4e38f, mx = -3.4e38f;
  for (int b = grp; b < 768; b += 4) {
    mn = fminf(mn, part[(size_t)b * 128 + dim]);
    mx = fmaxf(mx, part[(size_t)b * 128 + 64 + dim]);
  }
  __shared__ float smn[4][64];
  __shared__ float smx[4][64];
  smn[grp][dim] = mn;
  smx[grp][dim] = mx;
  __syncthreads();
  if (tid < 64) {
    const float m0 = fminf(fminf(smn[0][tid], smn[1][tid]), fminf(smn[2][tid], smn[3][tid]));
    const float M0 = fmaxf(fmaxf(smx[0][tid], smx[1][tid]), fmaxf(smx[2][tid], smx[3][tid]));
    const float rng = M0 - m0;
    float p = rng * rng;
#pragma unroll
    for (int off = 32; off > 0; off >>= 1) p += __shfl_xor(p, off, 64);
    if (tid == 0) ws[OFF_DIAM] = p;
  }
}

// ---------------- kernel 3: build cost matrices ----------------
// 64x64 tiles. blocks: [0,512) C_xy (+ transposed C_yx), [512,1536) C_xx, [1536,1792) C_yy
__global__ __launch_bounds__(256) void build_cost(float* __restrict__ ws) {
  const int b = blockIdx.x;
  const int tid = threadIdx.x;

  const float* A;
  const float* B;
  const float* nA;
  const float* nB;
  float* Cout;
  float* CoutT = nullptr;
  int ldc, ldcT = 0, ti, tj;

  const float* x = ws + OFF_X;
  const float* y = ws + OFF_X + (size_t)ND * DOUT;
  const float* nx = ws + OFF_NRM;
  const float* ny = ws + OFF_NRM + ND;

  if (b < 512) {                 // C_xy: 32 x 16 tiles
    ti = b >> 4; tj = b & 15;
    A = x; B = y; nA = nx; nB = ny;
    Cout = ws + OFF_CXY; ldc = NS;
    CoutT = ws + OFF_CYX; ldcT = ND;
  } else if (b < 1536) {         // C_xx: 32 x 32
    const int bb = b - 512;
    ti = bb >> 5; tj = bb & 31;
    A = x; B = x; nA = nx; nB = nx;
    Cout = ws + OFF_CXX; ldc = ND;
  } else {                       // C_yy: 16 x 16
    const int bb = b - 1536;
    ti = bb >> 4; tj = bb & 15;
    A = y; B = y; nA = ny; nB = ny;
    Cout = ws + OFF_CYY; ldc = NS;
  }

  __shared__ float Ast[64][68]; // transposed: Ast[k][row]
  __shared__ float Bst[64][68];

  for (int idx = tid; idx < 64 * 16; idx += 256) {
    const int row = idx >> 4;
    const int c4 = idx & 15;
    const float4 a = reinterpret_cast<const float4*>(A + (size_t)(ti * 64 + row) * DOUT)[c4];
    Ast[c4 * 4 + 0][row] = a.x;
    Ast[c4 * 4 + 1][row] = a.y;
    Ast[c4 * 4 + 2][row] = a.z;
    Ast[c4 * 4 + 3][row] = a.w;
    const float4 bv = reinterpret_cast<const float4*>(B + (size_t)(tj * 64 + row) * DOUT)[c4];
    Bst[c4 * 4 + 0][row] = bv.x;
    Bst[c4 * 4 + 1][row] = bv.y;
    Bst[c4 * 4 + 2][row] = bv.z;
    Bst[c4 * 4 + 3][row] = bv.w;
  }
  __syncthreads();

  const int tr = tid >> 4;
  const int tc = tid & 15;
  float acc[4][4] = {};
#pragma unroll 4
  for (int k = 0; k < 64; ++k) {
    float av[4], bv[4];
#pragma unroll
    for (int i = 0; i < 4; ++i) av[i] = Ast[k][tr * 4 + i];
#pragma unroll
    for (int j = 0; j < 4; ++j) bv[j] = Bst[k][tc * 4 + j];
#pragma unroll
    for (int i = 0; i < 4; ++i)
#pragma unroll
      for (int j = 0; j < 4; ++j) acc[i][j] = fmaf(av[i], bv[j], acc[i][j]);
  }

  float na[4], nb[4];
#pragma unroll
  for (int i = 0; i < 4; ++i) na[i] = nA[ti * 64 + tr * 4 + i];
#pragma unroll
  for (int j = 0; j < 4; ++j) nb[j] = nB[tj * 64 + tc * 4 + j];

#pragma unroll
  for (int i = 0; i < 4; ++i) {
    const int gi = ti * 64 + tr * 4 + i;
    float4 cv;
    cv.x = na[i] + nb[0] - acc[i][0];
    cv.y = na[i] + nb[1] - acc[i][1];
    cv.z = na[i] + nb[2] - acc[i][2];
    cv.w = na[i] + nb[3] - acc[i][3];
    reinterpret_cast<float4*>(Cout + (size_t)gi * ldc + tj * 64 + tc * 4)[0] = cv;
    if (CoutT) {
      const int gj = tj * 64 + tc * 4;
      CoutT[(size_t)(gj + 0) * ldcT + gi] = cv.x;
      CoutT[(size_t)(gj + 1) * ldcT + gi] = cv.y;
      CoutT[(size_t)(gj + 2) * ldcT + gi] = cv.z;
      CoutT[(size_t)(gj + 3) * ldcT + gi] = cv.w;
    }
  }
}

// ---------------- softmin row primitive ----------------
// f_i = -max_j(v) - eps*log( (1/LEN) * sum_j exp((v_j - max)/eps) ),  v_j = pot_j - C_ij
template <int LEN, bool USEPOT>
__device__ inline float softmin_row(const float* __restrict__ Crow,
                                    const float* __restrict__ pin,
                                    int lane, float eps, float inv_eps) {
  constexpr int NK = LEN / 256; // float4 chunks per lane
  float v[NK * 4];
  float m = -3.4e38f;
#pragma unroll
  for (int k = 0; k < NK; ++k) {
    const float4 c4 = reinterpret_cast<const float4*>(Crow)[k * 64 + lane];
    float4 p4 = make_float4(0.f, 0.f, 0.f, 0.f);
    if (USEPOT) p4 = reinterpret_cast<const float4*>(pin)[k * 64 + lane];
    v[4 * k + 0] = p4.x - c4.x;
    v[4 * k + 1] = p4.y - c4.y;
    v[4 * k + 2] = p4.z - c4.z;
    v[4 * k + 3] = p4.w - c4.w;
    m = fmaxf(m, fmaxf(fmaxf(v[4 * k + 0], v[4 * k + 1]), fmaxf(v[4 * k + 2], v[4 * k + 3])));
  }
#pragma unroll
  for (int off = 32; off > 0; off >>= 1) m = fmaxf(m, __shfl_xor(m, off, 64));
  float ssum = 0.f;
#pragma unroll
  for (int k = 0; k < NK * 4; ++k) ssum += __expf((v[k] - m) * inv_eps);
#pragma unroll
  for (int off = 32; off > 0; off >>= 1) ssum += __shfl_xor(ssum, off, 64);
  return -m - eps * __logf(ssum * (1.0f / (float)LEN));
}

// ---------------- kernel 4: one sinkhorn step ----------------
// mode 0: init (pot=0, no avg)            grid: 6144 waves
// mode 1: scan step (avg 0.5)             grid: 6144 waves
// mode 2: final A (f_ab, f_aa, g_bb)      grid: 5120 waves
// mode 3: final B (g_ab from NEW f_ab)    grid: 1024 waves
__global__ __launch_bounds__(256) void sinkhorn_step(float* ws,
                                                     const float* __restrict__ potIn,
                                                     float* __restrict__ potOut,
                                                     int t, int mode) {
  const int wave = blockIdx.x * 4 + (threadIdx.x >> 6);
  const int lane = threadIdx.x & 63;

  const float diam2 = ws[OFF_DIAM];
  float eps;
  if (mode >= 2) eps = BLUR2;
  else           eps = fmaxf(ldexpf(diam2, -2 * t), BLUR2);
  const float inv_eps = 1.0f / eps;

  const float* Crow;
  const float* pin;
  int outIdx, len;

  if (mode == 3) {
    const int j = wave;
    Crow = ws + OFF_CYX + (size_t)j * ND;  pin = potIn + 0;    outIdx = ND + j;       len = ND;
  } else if (mode == 2) {
    if (wave < 2048)      { Crow = ws + OFF_CXY + (size_t)wave * NS;            pin = potIn + 2048; outIdx = wave;              len = NS; }
    else if (wave < 4096) { const int i = wave - 2048; Crow = ws + OFF_CXX + (size_t)i * ND; pin = potIn + 3072; outIdx = 3072 + i; len = ND; }
    else                  { const int j = wave - 4096; Crow = ws + OFF_CYY + (size_t)j * NS; pin = potIn + 5120; outIdx = 5120 + j; len = NS; }
  } else {
    if (wave < 2048)      { Crow = ws + OFF_CXY + (size_t)wave * NS;            pin = potIn + 2048; outIdx = wave;              len = NS; }
    else if (wave < 3072) { const int j = wave - 2048; Crow = ws + OFF_CYX + (size_t)j * ND; pin = potIn + 0;    outIdx = 2048 + j; len = ND; }
    else if (wave < 5120) { const int i = wave - 3072; Crow = ws + OFF_CXX + (size_t)i * ND; pin = potIn + 3072; outIdx = 3072 + i; len = ND; }
    else                  { const int j = wave - 5120; Crow = ws + OFF_CYY + (size_t)j * NS; pin = potIn + 5120; outIdx = 5120 + j; len = NS; }
  }

  float f;
  if (mode == 0) {
    f = (len == NS) ? softmin_row<NS, false>(Crow, pin, lane, eps, inv_eps)
                    : softmin_row<ND, false>(Crow, pin, lane, eps, inv_eps);
  } else {
    f = (len == NS) ? softmin_row<NS, true>(Crow, pin, lane, eps, inv_eps)
                    : softmin_row<ND, true>(Crow, pin, lane, eps, inv_eps);
  }
  if (mode == 1) f = 0.5f * (potIn[outIdx] + f);
  if (lane == 0) potOut[outIdx] = f;
}

// ---------------- kernel 5: epilogue ----------------
__global__ __launch_bounds__(256) void epilogue_kernel(const float* __restrict__ pot,
                                                       float* __restrict__ out) {
  const int tid = threadIdx.x;
  float s1 = 0.f, s2 = 0.f;
  for (int i = tid; i < ND; i += 256) s1 += pot[i] - pot[3072 + i];
  for (int j = tid; j < NS; j += 256) s2 += pot[2048 + j] - pot[5120 + j];
  float part = s1 * (1.0f / (float)ND) + s2 * (1.0f / (float)NS);
#pragma unroll
  for (int off = 32; off > 0; off >>= 1) part += __shfl_xor(part, off, 64);
  __shared__ float sp[4];
  if ((tid & 63) == 0) sp[tid >> 6] = part;
  __syncthreads();
  if (tid == 0) out[0] = expf(-(sp[0] + sp[1] + sp[2] + sp[3]));
}

// ---------------- host ----------------
extern "C" void kernel_launch(void* const* d_in, const int* in_sizes, int n_in,
                              void* d_out, int out_size, void* d_ws, size_t ws_size,
                              hipStream_t stream) {
  const float* d = (const float*)d_in[0];
  const float* s = (const float*)d_in[1];
  const float* M = (const float*)d_in[2];
  float* out = (float*)d_out;
  float* ws = (float*)d_ws;

  float* pot0 = ws + OFF_POT0;
  float* pot1 = ws + OFF_POT1;

  proj_kernel<<<768, 256, 0, stream>>>(d, s, M, ws);
  stats_kernel<<<1, 256, 0, stream>>>(ws);
  build_cost<<<1792, 256, 0, stream>>>(ws);

  // init: writes pot0 (potIn unused in mode 0)
  sinkhorn_step<<<1536, 256, 0, stream>>>(ws, pot0, pot0, 0, 0);

  float* pin = pot0;
  float* pout = pot1;
  for (int t = 0; t < NSTEPS; ++t) {
    sinkhorn_step<<<1536, 256, 0, stream>>>(ws, pin, pout, t, 1);
    float* tmp = pin; pin = pout; pout = tmp;
  }
  // after 20 steps current potentials are in pot0 (pin == pot0)

  // final extrapolation: A then B (B needs the NEW f_ab)
  sinkhorn_step<<<1280, 256, 0, stream>>>(ws, pin, pout, 0, 2);
  sinkhorn_step<<<256, 256, 0, stream>>>(ws, pout, pout, 0, 3);

  epilogue_kernel<<<1, 256, 0, stream>>>(pout, out);
}

// Round 4
// 220.511 us; speedup vs baseline: 1.1852x; 1.1852x over previous
//
#include <hip/hip_runtime.h>
#include <math.h>

// ---------------- problem constants ----------------
#define ND 2048
#define NS 1024
#define DIN 768
#define DOUT 64
#define NSTEPS 20
static constexpr float BLUR2 = 0.05f * 0.05f; // blur^p, p=2

// ---------------- ws layout (float offsets) ----------------
// x rows [0,2048), y rows [2048,3072) contiguous, 64 cols each
#define OFF_X     0u              // 3072*64 = 196608
#define OFF_NRM   196608u         // 3072 (0.5*||row||^2), nx then ny
#define OFF_DIAM  199680u         // 1 (diameter^2), padded to 64
#define OFF_POT0  199744u         // 6144: [f_ab 2048 | g_ab 1024 | f_aa 2048 | g_bb 1024]
#define OFF_POT1  205888u         // 6144
#define OFF_CXY   212032u         // 2048*1024
#define OFF_CYX   2309184u        // 1024*2048
#define OFF_CXX   4406336u        // 2048*2048
#define OFF_CYY   8600640u        // 1024*1024  (end = 9649216 floats = 38.6 MB)
// global min/max key array (64 min keys | 64 max keys, uint-encoded floats)
// lives transiently in the C_xy region: seeded by init_mm, atomically updated
// by proj_kernel, consumed by stats_kernel, then overwritten by build_cost.
#define OFF_MM    OFF_CXY

// monotone float<->uint key encoding (order-preserving for atomicMin/Max)
__device__ inline unsigned fkey(float f) {
  const unsigned b = __float_as_uint(f);
  return (b & 0x80000000u) ? ~b : (b | 0x80000000u);
}
__device__ inline float funkey(unsigned k) {
  const unsigned b = (k & 0x80000000u) ? (k & 0x7FFFFFFFu) : ~k;
  return __uint_as_float(b);
}

// ---------------- kernel 0: seed min/max keys ----------------
__global__ __launch_bounds__(128) void init_mm(float* __restrict__ ws) {
  unsigned* mm = reinterpret_cast<unsigned*>(ws + OFF_MM);
  const int t = threadIdx.x;
  mm[t] = (t < 64) ? 0xFFFFFFFFu : 0u; // min-keys = +max, max-keys = 0 (= -inf key)
}

// ---------------- kernel 1: projection (K-split) + row sqnorms + atomic min/max ----
// 768 blocks x 4 waves. Block b owns rows 4b..4b+3; wave w owns K-chunk
// [192w, 192w+192). lane = output column. Partials combined via LDS.
__global__ __launch_bounds__(256) void proj_kernel(const float* __restrict__ d,
                                                   const float* __restrict__ s,
                                                   const float* __restrict__ M,
                                                   float* __restrict__ ws) {
  const int w    = threadIdx.x >> 6;
  const int lane = threadIdx.x & 63;
  const int r0   = blockIdx.x * 4; // rows r0..r0+3, all on same side of 2048

  const float* base;
  if (r0 < ND) base = d + (size_t)r0 * DIN;
  else         base = s + (size_t)(r0 - ND) * DIN;

  const float4* s0 = reinterpret_cast<const float4*>(base + 0 * DIN + w * 192);
  const float4* s1 = reinterpret_cast<const float4*>(base + 1 * DIN + w * 192);
  const float4* s2 = reinterpret_cast<const float4*>(base + 2 * DIN + w * 192);
  const float4* s3 = reinterpret_cast<const float4*>(base + 3 * DIN + w * 192);
  const float* Mw = M + (size_t)(w * 192) * DOUT + lane;

  float a0 = 0.f, a1 = 0.f, a2 = 0.f, a3 = 0.f;
#pragma unroll 4
  for (int kk = 0; kk < 48; ++kk) {
    const float4 r0v = s0[kk];
    const float4 r1v = s1[kk];
    const float4 r2v = s2[kk];
    const float4 r3v = s3[kk];
    const float m0 = Mw[(kk * 4 + 0) * DOUT];
    const float m1 = Mw[(kk * 4 + 1) * DOUT];
    const float m2 = Mw[(kk * 4 + 2) * DOUT];
    const float m3 = Mw[(kk * 4 + 3) * DOUT];
    a0 = fmaf(r0v.x, m0, a0); a0 = fmaf(r0v.y, m1, a0);
    a0 = fmaf(r0v.z, m2, a0); a0 = fmaf(r0v.w, m3, a0);
    a1 = fmaf(r1v.x, m0, a1); a1 = fmaf(r1v.y, m1, a1);
    a1 = fmaf(r1v.z, m2, a1); a1 = fmaf(r1v.w, m3, a1);
    a2 = fmaf(r2v.x, m0, a2); a2 = fmaf(r2v.y, m1, a2);
    a2 = fmaf(r2v.z, m2, a2); a2 = fmaf(r2v.w, m3, a2);
    a3 = fmaf(r3v.x, m0, a3); a3 = fmaf(r3v.y, m1, a3);
    a3 = fmaf(r3v.z, m2, a3); a3 = fmaf(r3v.w, m3, a3);
  }

  __shared__ float part[4][4][64];
  part[w][0][lane] = a0;
  part[w][1][lane] = a1;
  part[w][2][lane] = a2;
  part[w][3][lane] = a3;
  __syncthreads();

  if (w == 0) {
    const float f0 = part[0][0][lane] + part[1][0][lane] + part[2][0][lane] + part[3][0][lane];
    const float f1 = part[0][1][lane] + part[1][1][lane] + part[2][1][lane] + part[3][1][lane];
    const float f2 = part[0][2][lane] + part[1][2][lane] + part[2][2][lane] + part[3][2][lane];
    const float f3 = part[0][3][lane] + part[1][3][lane] + part[2][3][lane] + part[3][3][lane];

    float* xy = ws + OFF_X;
    xy[(size_t)(r0 + 0) * DOUT + lane] = f0;
    xy[(size_t)(r0 + 1) * DOUT + lane] = f1;
    xy[(size_t)(r0 + 2) * DOUT + lane] = f2;
    xy[(size_t)(r0 + 3) * DOUT + lane] = f3;

    // per-dim min/max over the 4 final rows -> global atomic reduce
    const float mn4 = fminf(fminf(f0, f1), fminf(f2, f3));
    const float mx4 = fmaxf(fmaxf(f0, f1), fmaxf(f2, f3));
    unsigned* mm = reinterpret_cast<unsigned*>(ws + OFF_MM);
    atomicMin(mm + lane, fkey(mn4));
    atomicMax(mm + 64 + lane, fkey(mx4));

    float n0 = f0 * f0, n1 = f1 * f1, n2 = f2 * f2, n3 = f3 * f3;
#pragma unroll
    for (int off = 32; off > 0; off >>= 1) {
      n0 += __shfl_xor(n0, off, 64);
      n1 += __shfl_xor(n1, off, 64);
      n2 += __shfl_xor(n2, off, 64);
      n3 += __shfl_xor(n3, off, 64);
    }
    if (lane == 0) {
      float* nrm = ws + OFF_NRM;
      nrm[r0 + 0] = 0.5f * n0;
      nrm[r0 + 1] = 0.5f * n1;
      nrm[r0 + 2] = 0.5f * n2;
      nrm[r0 + 3] = 0.5f * n3;
    }
  }
}

// ---------------- kernel 2: min/max keys -> diameter^2 (one wave) ----------------
__global__ __launch_bounds__(64) void stats_kernel(float* __restrict__ ws) {
  const int lane = threadIdx.x;
  const unsigned* mm = reinterpret_cast<const unsigned*>(ws + OFF_MM);
  const float mn = funkey(mm[lane]);
  const float mx = funkey(mm[64 + lane]);
  const float rng = mx - mn;
  float p = rng * rng;
#pragma unroll
  for (int off = 32; off > 0; off >>= 1) p += __shfl_xor(p, off, 64);
  if (lane == 0) ws[OFF_DIAM] = p;
}

// ---------------- kernel 3: build cost matrices ----------------
// 64x64 tiles. blocks: [0,512) C_xy (+ transposed C_yx), [512,1536) C_xx, [1536,1792) C_yy
__global__ __launch_bounds__(256) void build_cost(float* __restrict__ ws) {
  const int b = blockIdx.x;
  const int tid = threadIdx.x;

  const float* A;
  const float* B;
  const float* nA;
  const float* nB;
  float* Cout;
  float* CoutT = nullptr;
  int ldc, ldcT = 0, ti, tj;

  const float* x = ws + OFF_X;
  const float* y = ws + OFF_X + (size_t)ND * DOUT;
  const float* nx = ws + OFF_NRM;
  const float* ny = ws + OFF_NRM + ND;

  if (b < 512) {                 // C_xy: 32 x 16 tiles
    ti = b >> 4; tj = b & 15;
    A = x; B = y; nA = nx; nB = ny;
    Cout = ws + OFF_CXY; ldc = NS;
    CoutT = ws + OFF_CYX; ldcT = ND;
  } else if (b < 1536) {         // C_xx: 32 x 32
    const int bb = b - 512;
    ti = bb >> 5; tj = bb & 31;
    A = x; B = x; nA = nx; nB = nx;
    Cout = ws + OFF_CXX; ldc = ND;
  } else {                       // C_yy: 16 x 16
    const int bb = b - 1536;
    ti = bb >> 4; tj = bb & 15;
    A = y; B = y; nA = ny; nB = ny;
    Cout = ws + OFF_CYY; ldc = NS;
  }

  __shared__ float Ast[64][68]; // transposed: Ast[k][row]
  __shared__ float Bst[64][68];

  for (int idx = tid; idx < 64 * 16; idx += 256) {
    const int row = idx >> 4;
    const int c4 = idx & 15;
    const float4 a = reinterpret_cast<const float4*>(A + (size_t)(ti * 64 + row) * DOUT)[c4];
    Ast[c4 * 4 + 0][row] = a.x;
    Ast[c4 * 4 + 1][row] = a.y;
    Ast[c4 * 4 + 2][row] = a.z;
    Ast[c4 * 4 + 3][row] = a.w;
    const float4 bv = reinterpret_cast<const float4*>(B + (size_t)(tj * 64 + row) * DOUT)[c4];
    Bst[c4 * 4 + 0][row] = bv.x;
    Bst[c4 * 4 + 1][row] = bv.y;
    Bst[c4 * 4 + 2][row] = bv.z;
    Bst[c4 * 4 + 3][row] = bv.w;
  }
  __syncthreads();

  const int tr = tid >> 4;
  const int tc = tid & 15;
  float acc[4][4] = {};
#pragma unroll 4
  for (int k = 0; k < 64; ++k) {
    float av[4], bv[4];
#pragma unroll
    for (int i = 0; i < 4; ++i) av[i] = Ast[k][tr * 4 + i];
#pragma unroll
    for (int j = 0; j < 4; ++j) bv[j] = Bst[k][tc * 4 + j];
#pragma unroll
    for (int i = 0; i < 4; ++i)
#pragma unroll
      for (int j = 0; j < 4; ++j) acc[i][j] = fmaf(av[i], bv[j], acc[i][j]);
  }

  float na[4], nb[4];
#pragma unroll
  for (int i = 0; i < 4; ++i) na[i] = nA[ti * 64 + tr * 4 + i];
#pragma unroll
  for (int j = 0; j < 4; ++j) nb[j] = nB[tj * 64 + tc * 4 + j];

#pragma unroll
  for (int i = 0; i < 4; ++i) {
    const int gi = ti * 64 + tr * 4 + i;
    float4 cv;
    cv.x = na[i] + nb[0] - acc[i][0];
    cv.y = na[i] + nb[1] - acc[i][1];
    cv.z = na[i] + nb[2] - acc[i][2];
    cv.w = na[i] + nb[3] - acc[i][3];
    reinterpret_cast<float4*>(Cout + (size_t)gi * ldc + tj * 64 + tc * 4)[0] = cv;
    if (CoutT) {
      const int gj = tj * 64 + tc * 4;
      CoutT[(size_t)(gj + 0) * ldcT + gi] = cv.x;
      CoutT[(size_t)(gj + 1) * ldcT + gi] = cv.y;
      CoutT[(size_t)(gj + 2) * ldcT + gi] = cv.z;
      CoutT[(size_t)(gj + 3) * ldcT + gi] = cv.w;
    }
  }
}

// ---------------- softmin row primitive ----------------
// f_i = -max_j(v) - eps*log( (1/LEN) * sum_j exp((v_j - max)/eps) ),  v_j = pot_j - C_ij
template <int LEN, bool USEPOT>
__device__ inline float softmin_row(const float* __restrict__ Crow,
                                    const float* __restrict__ pin,
                                    int lane, float eps, float inv_eps) {
  constexpr int NK = LEN / 256; // float4 chunks per lane
  float v[NK * 4];
  float m = -3.4e38f;
#pragma unroll
  for (int k = 0; k < NK; ++k) {
    const float4 c4 = reinterpret_cast<const float4*>(Crow)[k * 64 + lane];
    float4 p4 = make_float4(0.f, 0.f, 0.f, 0.f);
    if (USEPOT) p4 = reinterpret_cast<const float4*>(pin)[k * 64 + lane];
    v[4 * k + 0] = p4.x - c4.x;
    v[4 * k + 1] = p4.y - c4.y;
    v[4 * k + 2] = p4.z - c4.z;
    v[4 * k + 3] = p4.w - c4.w;
    m = fmaxf(m, fmaxf(fmaxf(v[4 * k + 0], v[4 * k + 1]), fmaxf(v[4 * k + 2], v[4 * k + 3])));
  }
#pragma unroll
  for (int off = 32; off > 0; off >>= 1) m = fmaxf(m, __shfl_xor(m, off, 64));
  float ssum = 0.f;
#pragma unroll
  for (int k = 0; k < NK * 4; ++k) ssum += __expf((v[k] - m) * inv_eps);
#pragma unroll
  for (int off = 32; off > 0; off >>= 1) ssum += __shfl_xor(ssum, off, 64);
  return -m - eps * __logf(ssum * (1.0f / (float)LEN));
}

// ---------------- kernel 4: one sinkhorn step ----------------
// mode 0: init (pot=0, no avg)            grid: 6144 waves
// mode 1: scan step (avg 0.5)             grid: 6144 waves
// mode 2: final A (f_ab, f_aa, g_bb)      grid: 5120 waves
// mode 3: final B (g_ab from NEW f_ab)    grid: 1024 waves
__global__ __launch_bounds__(256) void sinkhorn_step(float* ws,
                                                     const float* __restrict__ potIn,
                                                     float* __restrict__ potOut,
                                                     int t, int mode) {
  const int wave = blockIdx.x * 4 + (threadIdx.x >> 6);
  const int lane = threadIdx.x & 63;

  const float diam2 = ws[OFF_DIAM];
  float eps;
  if (mode >= 2) eps = BLUR2;
  else           eps = fmaxf(ldexpf(diam2, -2 * t), BLUR2);
  const float inv_eps = 1.0f / eps;

  const float* Crow;
  const float* pin;
  int outIdx, len;

  if (mode == 3) {
    const int j = wave;
    Crow = ws + OFF_CYX + (size_t)j * ND;  pin = potIn + 0;    outIdx = ND + j;       len = ND;
  } else if (mode == 2) {
    if (wave < 2048)      { Crow = ws + OFF_CXY + (size_t)wave * NS;            pin = potIn + 2048; outIdx = wave;              len = NS; }
    else if (wave < 4096) { const int i = wave - 2048; Crow = ws + OFF_CXX + (size_t)i * ND; pin = potIn + 3072; outIdx = 3072 + i; len = ND; }
    else                  { const int j = wave - 4096; Crow = ws + OFF_CYY + (size_t)j * NS; pin = potIn + 5120; outIdx = 5120 + j; len = NS; }
  } else {
    if (wave < 2048)      { Crow = ws + OFF_CXY + (size_t)wave * NS;            pin = potIn + 2048; outIdx = wave;              len = NS; }
    else if (wave < 3072) { const int j = wave - 2048; Crow = ws + OFF_CYX + (size_t)j * ND; pin = potIn + 0;    outIdx = 2048 + j; len = ND; }
    else if (wave < 5120) { const int i = wave - 3072; Crow = ws + OFF_CXX + (size_t)i * ND; pin = potIn + 3072; outIdx = 3072 + i; len = ND; }
    else                  { const int j = wave - 5120; Crow = ws + OFF_CYY + (size_t)j * NS; pin = potIn + 5120; outIdx = 5120 + j; len = NS; }
  }

  float f;
  if (mode == 0) {
    f = (len == NS) ? softmin_row<NS, false>(Crow, pin, lane, eps, inv_eps)
                    : softmin_row<ND, false>(Crow, pin, lane, eps, inv_eps);
  } else {
    f = (len == NS) ? softmin_row<NS, true>(Crow, pin, lane, eps, inv_eps)
                    : softmin_row<ND, true>(Crow, pin, lane, eps, inv_eps);
  }
  if (mode == 1) f = 0.5f * (potIn[outIdx] + f);
  if (lane == 0) potOut[outIdx] = f;
}

// ---------------- kernel 5: epilogue ----------------
__global__ __launch_bounds__(256) void epilogue_kernel(const float* __restrict__ pot,
                                                       float* __restrict__ out) {
  const int tid = threadIdx.x;
  float s1 = 0.f, s2 = 0.f;
  for (int i = tid; i < ND; i += 256) s1 += pot[i] - pot[3072 + i];
  for (int j = tid; j < NS; j += 256) s2 += pot[2048 + j] - pot[5120 + j];
  float part = s1 * (1.0f / (float)ND) + s2 * (1.0f / (float)NS);
#pragma unroll
  for (int off = 32; off > 0; off >>= 1) part += __shfl_xor(part, off, 64);
  __shared__ float sp[4];
  if ((tid & 63) == 0) sp[tid >> 6] = part;
  __syncthreads();
  if (tid == 0) out[0] = expf(-(sp[0] + sp[1] + sp[2] + sp[3]));
}

// ---------------- host ----------------
extern "C" void kernel_launch(void* const* d_in, const int* in_sizes, int n_in,
                              void* d_out, int out_size, void* d_ws, size_t ws_size,
                              hipStream_t stream) {
  const float* d = (const float*)d_in[0];
  const float* s = (const float*)d_in[1];
  const float* M = (const float*)d_in[2];
  float* out = (float*)d_out;
  float* ws = (float*)d_ws;

  float* pot0 = ws + OFF_POT0;
  float* pot1 = ws + OFF_POT1;

  init_mm<<<1, 128, 0, stream>>>(ws);
  proj_kernel<<<768, 256, 0, stream>>>(d, s, M, ws);
  stats_kernel<<<1, 64, 0, stream>>>(ws);
  build_cost<<<1792, 256, 0, stream>>>(ws);

  // init: writes pot0 (potIn unused in mode 0)
  sinkhorn_step<<<1536, 256, 0, stream>>>(ws, pot0, pot0, 0, 0);

  float* pin = pot0;
  float* pout = pot1;
  for (int t = 0; t < NSTEPS; ++t) {
    sinkhorn_step<<<1536, 256, 0, stream>>>(ws, pin, pout, t, 1);
    float* tmp = pin; pin = pout; pout = tmp;
  }
  // after 20 steps current potentials are in pot0 (pin == pot0)

  // final extrapolation: A then B (B needs the NEW f_ab)
  sinkhorn_step<<<1280, 256, 0, stream>>>(ws, pin, pout, 0, 2);
  sinkhorn_step<<<256, 256, 0, stream>>>(ws, pout, pout, 0, 3);

  epilogue_kernel<<<1, 256, 0, stream>>>(pout, out);
}